// Round 11
// baseline (71.153 us; speedup 1.0000x reference)
//
#include <hip/hip_runtime.h>
#include <hip/hip_bf16.h>

// Problem constants (fixed by setup_inputs)
#define BATCH 4
#define NNODES 4096
#define HID 256
#define NHEADS 8
#define DH 32
#define DEG 16
#define NEDGES (BATCH * NNODES * DEG)   // 262144
#define NROWS (BATCH * NNODES)          // 16384 node-rows

typedef __attribute__((ext_vector_type(8))) short short8;
typedef __attribute__((ext_vector_type(8))) unsigned short ushort8;
typedef __attribute__((ext_vector_type(4))) unsigned short u16x4;  // 'ushort4' collides with HIP types
typedef __attribute__((ext_vector_type(4))) float f32x4;

static __device__ __forceinline__ unsigned short f2bf(float f) {
  __hip_bfloat16 h = __float2bfloat16(f);  // RNE
  return *reinterpret_cast<unsigned short*>(&h);
}
static __device__ __forceinline__ float bf2f(unsigned short u) {
  unsigned int v = ((unsigned int)u) << 16;
  return *reinterpret_cast<float*>(&v);
}

// ---------------------------------------------------------------------------
// Prep: X -> bf16 row-major Xb (blocks [0,2048)); Wt fragment-ordered bf16
// (96 blocks):
//   Wt[(mat*4+strip)*16384 + kk*2048 + hi*512 + col*8 + j]
//     = bf16( W_mat[kk*32 + hi*8 + j][strip*64 + col] )
// ---------------------------------------------------------------------------
#define XBLOCKS 2048
#define WBLOCKS 96
__global__ __launch_bounds__(256) void prep_kernel(
    const float* __restrict__ X,
    const float* __restrict__ Wq, const float* __restrict__ Wk,
    const float* __restrict__ Wv,
    unsigned short* __restrict__ Xb, unsigned short* __restrict__ Wt) {
  const int tid = threadIdx.x;
  if (blockIdx.x < XBLOCKS) {
    const size_t base = (size_t)blockIdx.x * 2048 + (size_t)tid * 8;
    const float4 a = *reinterpret_cast<const float4*>(&X[base]);
    const float4 b = *reinterpret_cast<const float4*>(&X[base + 4]);
    ushort8 o;
    o[0] = f2bf(a.x); o[1] = f2bf(a.y); o[2] = f2bf(a.z); o[3] = f2bf(a.w);
    o[4] = f2bf(b.x); o[5] = f2bf(b.y); o[6] = f2bf(b.z); o[7] = f2bf(b.w);
    *reinterpret_cast<ushort8*>(&Xb[base]) = o;
  } else {
    const int o = (blockIdx.x - XBLOCKS) * 2048 + tid * 8;  // [0, 196608)
    const int mat   = o >> 16;
    const int w     = o & 65535;
    const int strip = w >> 14;
    const int r     = w & 16383;
    const int kk    = r >> 11;
    const int hi    = (r >> 9) & 3;
    const int col   = (r >> 3) & 63;
    const int k0    = kk * 32 + hi * 8;
    const int c     = strip * 64 + col;
    const float* __restrict__ W = (mat == 0) ? Wq : (mat == 1) ? Wk : Wv;
    ushort8 ovec;
    #pragma unroll
    for (int j = 0; j < 8; ++j) {
      ovec[j] = f2bf(W[(size_t)(k0 + j) * HID + c]);
    }
    *reinterpret_cast<ushort8*>(&Wt[o]) = ovec;
  }
}

// ---------------------------------------------------------------------------
// QKV projection: PERSISTENT PIPELINED blocks. Grid 768 = 8 XCD x 96 locals
// = exactly 3 blocks/CU, entire grid co-resident (no generations).
//   ll = bx>>3: (mat,cs) = ll%12, sub = ll/12 (0..7)
//   block's chunks: chunk(it) = sub*32 + xcd*4 + it, it=0..3  (bijective).
// The 12 (m,cs)-blocks sharing (xcd,sub) read the SAME A rows -> L2-hot.
// Per block: stage W strip (32KB LDS, linear conflict-free copy, ONCE),
// then 4 fully-unrolled chunk iterations with A PING-PONG PREFETCH:
// next chunk's 8 A-loads issue before current chunk's 16 ds_read + 32 MFMA
// -> HBM latency hides under compute instead of serializing (G15).
// MFMA operands swapped: mfma(Bf, Af) -> lane&15 = X-row, hi*4+reg = 4
// consecutive W-cols -> float4 (Q) / packed bf16x4 (K,V) stores.
// ---------------------------------------------------------------------------
__global__ __launch_bounds__(256, 3) void qkv_mfma_kernel(
    const unsigned short* __restrict__ Xb, const unsigned short* __restrict__ Wt,
    const float* __restrict__ bq, const float* __restrict__ bk,
    const float* __restrict__ bv,
    float* __restrict__ Qs, unsigned short* __restrict__ Kb,
    unsigned short* __restrict__ Vb) {
  __shared__ unsigned short sW[16384];  // 32 KB

  const int tid = threadIdx.x;
  const int xcd = blockIdx.x & 7;
  const int ll = blockIdx.x >> 3;       // 0..95
  const int s = ll % 12;
  const int sub = ll / 12;              // 0..7
  const int mat = s >> 2;               // 0=Q 1=K 2=V
  const int cs = s & 3;
  const int c0 = cs * 64;
  const int chunk0 = sub * 32 + xcd * 4;

  // --- Stage W strip once: linear conflict-free copy of pre-permuted bf16.
  const unsigned short* __restrict__ Wsrc = Wt + (size_t)(mat * 4 + cs) * 16384;
  #pragma unroll
  for (int i = 0; i < 8; ++i) {
    const int e = i * 2048 + tid * 8;
    *reinterpret_cast<ushort8*>(&sW[e]) =
        *reinterpret_cast<const ushort8*>(&Wsrc[e]);
  }

  const int lane = tid & 63;
  const int wv = tid >> 6;
  const int lm = lane & 15;
  const int hi = lane >> 4;             // 0..3
  const int lk = hi * 8;
  const int rbase = wv * 16 + lm;       // row offset within a chunk

  const float* __restrict__ bias = (mat == 0) ? bq : (mat == 1) ? bk : bv;
  float4 b4v[4];
  #pragma unroll
  for (int nt = 0; nt < 4; ++nt) {
    b4v[nt] = *reinterpret_cast<const float4*>(&bias[c0 + nt * 16 + hi * 4]);
  }

  // --- A ping-pong buffers (static names; full unroll keeps indexing static).
  short8 Aa[8], Ab[8];
  {
    const int row = chunk0 * 64 + rbase;
    #pragma unroll
    for (int kk = 0; kk < 8; ++kk) {
      Aa[kk] = *reinterpret_cast<const short8*>(
          &Xb[(size_t)row * 256 + kk * 32 + lk]);
    }
  }
  __syncthreads();  // W staged

  #pragma unroll
  for (int it = 0; it < 4; ++it) {
    // Prefetch next chunk's A into the other buffer (issues before MFMAs).
    if (it < 3) {
      const int rown = (chunk0 + it + 1) * 64 + rbase;
      #pragma unroll
      for (int kk = 0; kk < 8; ++kk) {
        if (it & 1) {
          Aa[kk] = *reinterpret_cast<const short8*>(
              &Xb[(size_t)rown * 256 + kk * 32 + lk]);
        } else {
          Ab[kk] = *reinterpret_cast<const short8*>(
              &Xb[(size_t)rown * 256 + kk * 32 + lk]);
        }
      }
    }
    const int row = (chunk0 + it) * 64 + rbase;

    #pragma unroll
    for (int nt = 0; nt < 4; ++nt) {
      short8 Bf[8];
      #pragma unroll
      for (int kk = 0; kk < 8; ++kk) {
        Bf[kk] = *reinterpret_cast<const short8*>(
            &sW[kk * 2048 + hi * 512 + (nt * 16 + lm) * 8]);
      }
      f32x4 acc = {0.f, 0.f, 0.f, 0.f};
      #pragma unroll
      for (int kk = 0; kk < 8; ++kk) {
        acc = __builtin_amdgcn_mfma_f32_16x16x32_bf16(
            Bf[kk], (it & 1) ? Ab[kk] : Aa[kk], acc, 0, 0, 0);
      }
      const int col0 = c0 + nt * 16 + hi * 4;
      const float4 b4 = b4v[nt];
      if (mat == 0) {
        float4 o;
        o.x = acc[0] + b4.x; o.y = acc[1] + b4.y;
        o.z = acc[2] + b4.z; o.w = acc[3] + b4.w;
        *reinterpret_cast<float4*>(&Qs[(size_t)row * 256 + col0]) = o;
      } else {
        u16x4 o;
        o[0] = f2bf(acc[0] + b4.x); o[1] = f2bf(acc[1] + b4.y);
        o[2] = f2bf(acc[2] + b4.z); o[3] = f2bf(acc[3] + b4.w);
        unsigned short* __restrict__ dst = (mat == 1) ? Kb : Vb;
        *reinterpret_cast<u16x4*>(&dst[(size_t)row * 256 + col0]) = o;
      }
    }
  }
}

// ---------------------------------------------------------------------------
// Attention (unchanged from R10). One block per segment, 256 threads =
// 4 waves; wave wv owns heads {2wv, 2wv+1} in both phases -> s_w handoff is
// wave-local (LDS fence only, no barrier). Lane map: lane = j*4 + hh*2 + p.
// Softmax without max-subtraction (inputs normalized; validated R10).
// XCD swizzle: each XCD works one batch -> K/V L2 locality.
// ---------------------------------------------------------------------------
__global__ __launch_bounds__(256) void attn_kernel(
    const float* __restrict__ Q, const unsigned short* __restrict__ K,
    const unsigned short* __restrict__ V, const int* __restrict__ edges,
    float* __restrict__ out) {
  __shared__ float s_w[DEG * NHEADS];   // [j][h], 512 B

  const int bx = blockIdx.x;
  const int xcd = bx & 7;
  const int g = (xcd >> 1) * NNODES + (((bx >> 3) << 1) | (xcd & 1));
  const int e0 = g * DEG;
  const int tid = threadIdx.x;

  const int b = edges[e0];                            // block-uniform
  const int qrow = b * NNODES + edges[NEDGES + e0];   // block-uniform

  // ---- Phase 1 + in-wave softmax ----
  const int lane = tid & 63;
  const int wv = tid >> 6;
  const int j = lane >> 2;
  const int hh = (lane >> 1) & 1;
  const int p = lane & 1;
  const int h = wv * 2 + hh;
  const int ch0 = h * 32 + p * 16;

  const int nsrc = b * NNODES + edges[2 * NEDGES + e0 + j];  // 16 distinct, coalesced

  const float* __restrict__ qp = &Q[(size_t)qrow * HID + ch0];
  const float4 q0 = *reinterpret_cast<const float4*>(qp);
  const float4 q1 = *reinterpret_cast<const float4*>(qp + 4);
  const float4 q2 = *reinterpret_cast<const float4*>(qp + 8);
  const float4 q3 = *reinterpret_cast<const float4*>(qp + 12);
  const unsigned short* __restrict__ kp = &K[(size_t)nsrc * HID + ch0];
  const ushort8 k0 = *reinterpret_cast<const ushort8*>(kp);
  const ushort8 k1 = *reinterpret_cast<const ushort8*>(kp + 8);

  float partial;
  partial  = q0.x * bf2f(k0[0]); partial = fmaf(q0.y, bf2f(k0[1]), partial);
  partial = fmaf(q0.z, bf2f(k0[2]), partial); partial = fmaf(q0.w, bf2f(k0[3]), partial);
  partial = fmaf(q1.x, bf2f(k0[4]), partial); partial = fmaf(q1.y, bf2f(k0[5]), partial);
  partial = fmaf(q1.z, bf2f(k0[6]), partial); partial = fmaf(q1.w, bf2f(k0[7]), partial);
  partial = fmaf(q2.x, bf2f(k1[0]), partial); partial = fmaf(q2.y, bf2f(k1[1]), partial);
  partial = fmaf(q2.z, bf2f(k1[2]), partial); partial = fmaf(q2.w, bf2f(k1[3]), partial);
  partial = fmaf(q3.x, bf2f(k1[4]), partial); partial = fmaf(q3.y, bf2f(k1[5]), partial);
  partial = fmaf(q3.z, bf2f(k1[6]), partial); partial = fmaf(q3.w, bf2f(k1[7]), partial);

  partial += __shfl_xor(partial, 1);                 // combine p-halves
  const float sc = partial * 0.17677669529663687f;   // 1/sqrt(DH)

  const float e = __expf(sc);                        // no max shift (safe: |sc| small)
  float sum = e;
  sum += __shfl_xor(sum, 4);
  sum += __shfl_xor(sum, 8);
  sum += __shfl_xor(sum, 16);
  sum += __shfl_xor(sum, 32);

  if (p == 0) s_w[j * NHEADS + h] = e / sum;
  // Wave-local handoff: fence LDS, no all-wave barrier needed.
  asm volatile("s_waitcnt lgkmcnt(0)" ::: "memory");

  // ---- Phase 3: weighted V gather-sum (tid = channel) ----
  const int h3 = tid >> 5;
  float acc = 0.0f;
  #pragma unroll
  for (int jj = 0; jj < DEG; ++jj) {
    const int n = b * NNODES + edges[2 * NEDGES + e0 + jj];  // uniform scalar loads
    acc = fmaf(s_w[jj * NHEADS + h3], bf2f(V[(size_t)n * HID + tid]), acc);
  }
  out[(size_t)qrow * HID + tid] = acc;
}

// ---------------------------------------------------------------------------
extern "C" void kernel_launch(void* const* d_in, const int* in_sizes, int n_in,
                              void* d_out, int out_size, void* d_ws, size_t ws_size,
                              hipStream_t stream) {
  const float* X     = (const float*)d_in[0];
  const int*   edges = (const int*)d_in[1];
  const float* Wq    = (const float*)d_in[2];
  const float* bq    = (const float*)d_in[3];
  const float* Wk    = (const float*)d_in[4];
  const float* bk    = (const float*)d_in[5];
  const float* Wv    = (const float*)d_in[6];
  const float* bv    = (const float*)d_in[7];
  float* out = (float*)d_out;

  // Workspace: Qs fp32 16MiB | Kb bf16 8MiB | Vb bf16 8MiB | Xb bf16 8MiB |
  //            Wt bf16 384KiB  (~40.4 MiB total)
  char* w = (char*)d_ws;
  float*          Qs = (float*)w;                 w += (size_t)NROWS * HID * 4;
  unsigned short* Kb = (unsigned short*)w;        w += (size_t)NROWS * HID * 2;
  unsigned short* Vb = (unsigned short*)w;        w += (size_t)NROWS * HID * 2;
  unsigned short* Xb = (unsigned short*)w;        w += (size_t)NROWS * HID * 2;
  unsigned short* Wt = (unsigned short*)w;

  prep_kernel<<<XBLOCKS + WBLOCKS, 256, 0, stream>>>(X, Wq, Wk, Wv, Xb, Wt);
  qkv_mfma_kernel<<<768, 256, 0, stream>>>(Xb, Wt, bq, bk, bv, Qs, Kb, Vb);
  attn_kernel<<<NROWS, 256, 0, stream>>>(Qs, Kb, Vb, edges, out);
}

// Round 12
// 62.376 us; speedup vs baseline: 1.1407x; 1.1407x over previous
//
#include <hip/hip_runtime.h>
#include <hip/hip_bf16.h>

// Problem constants (fixed by setup_inputs)
#define BATCH 4
#define NNODES 4096
#define HID 256
#define NHEADS 8
#define DH 32
#define DEG 16
#define NEDGES (BATCH * NNODES * DEG)   // 262144
#define NROWS (BATCH * NNODES)          // 16384 node-rows

typedef __attribute__((ext_vector_type(8))) short short8;
typedef __attribute__((ext_vector_type(8))) unsigned short ushort8;
typedef __attribute__((ext_vector_type(4))) unsigned short u16x4;  // 'ushort4' collides with HIP types
typedef __attribute__((ext_vector_type(4))) float f32x4;

static __device__ __forceinline__ unsigned short f2bf(float f) {
  __hip_bfloat16 h = __float2bfloat16(f);  // RNE
  return *reinterpret_cast<unsigned short*>(&h);
}
static __device__ __forceinline__ float bf2f(unsigned short u) {
  unsigned int v = ((unsigned int)u) << 16;
  return *reinterpret_cast<float*>(&v);
}

// ---------------------------------------------------------------------------
// Prep (R5-exact): X -> bf16 row-major Xb (blocks [0,2048)); Wt
// fragment-ordered bf16 (96 blocks):
//   Wt[(mat*4+strip)*16384 + kk*2048 + hi*512 + col*8 + j]
//     = bf16( W_mat[kk*32 + hi*8 + j][strip*64 + col] )
// ---------------------------------------------------------------------------
#define XBLOCKS 2048
#define WBLOCKS 96
__global__ __launch_bounds__(256) void prep_kernel(
    const float* __restrict__ X,
    const float* __restrict__ Wq, const float* __restrict__ Wk,
    const float* __restrict__ Wv,
    unsigned short* __restrict__ Xb, unsigned short* __restrict__ Wt) {
  const int tid = threadIdx.x;
  if (blockIdx.x < XBLOCKS) {
    const size_t base = (size_t)blockIdx.x * 2048 + (size_t)tid * 8;
    const float4 a = *reinterpret_cast<const float4*>(&X[base]);
    const float4 b = *reinterpret_cast<const float4*>(&X[base + 4]);
    ushort8 o;
    o[0] = f2bf(a.x); o[1] = f2bf(a.y); o[2] = f2bf(a.z); o[3] = f2bf(a.w);
    o[4] = f2bf(b.x); o[5] = f2bf(b.y); o[6] = f2bf(b.z); o[7] = f2bf(b.w);
    *reinterpret_cast<ushort8*>(&Xb[base]) = o;
  } else {
    const int o = (blockIdx.x - XBLOCKS) * 2048 + tid * 8;  // [0, 196608)
    const int mat   = o >> 16;
    const int w     = o & 65535;
    const int strip = w >> 14;
    const int r     = w & 16383;
    const int kk    = r >> 11;
    const int hi    = (r >> 9) & 3;
    const int col   = (r >> 3) & 63;
    const int k0    = kk * 32 + hi * 8;
    const int c     = strip * 64 + col;
    const float* __restrict__ W = (mat == 0) ? Wq : (mat == 1) ? Wk : Wv;
    ushort8 ovec;
    #pragma unroll
    for (int j = 0; j < 8; ++j) {
      ovec[j] = f2bf(W[(size_t)(k0 + j) * HID + c]);
    }
    *reinterpret_cast<ushort8*>(&Wt[o]) = ovec;
  }
}

// ---------------------------------------------------------------------------
// QKV projection (R5-exact revert — the best measured variant, ~26 us).
// Grid 3072, STRIP-MAJOR: s = bx>>8 (mat = s>>2, cols [(s&3)*64,+64)),
// chunk = bx&255 (64 rows). No XCD remapping.
// Per block: stage W strip (32KB LDS, linear conflict-free copy), A-frags
// once per wave (16 rows), 4 nt-tiles x 8 MFMA (swapped operands), vector
// stores: float4 (Q) / packed bf16x4 (K,V).
// ---------------------------------------------------------------------------
__global__ __launch_bounds__(256, 4) void qkv_mfma_kernel(
    const unsigned short* __restrict__ Xb, const unsigned short* __restrict__ Wt,
    const float* __restrict__ bq, const float* __restrict__ bk,
    const float* __restrict__ bv,
    float* __restrict__ Qs, unsigned short* __restrict__ Kb,
    unsigned short* __restrict__ Vb) {
  __shared__ unsigned short sW[16384];  // 32 KB

  const int tid = threadIdx.x;
  const int s = blockIdx.x >> 8;        // 0..11  (strip-major)
  const int chunk = blockIdx.x & 255;   // 0..255
  const int mat = s >> 2;               // 0=Q 1=K 2=V
  const int c0 = (s & 3) * 64;

  // Stage W strip: linear coalesced copy (pre-permuted fragment order).
  const unsigned short* __restrict__ Wsrc = Wt + (size_t)(mat * 4 + (s & 3)) * 16384;
  #pragma unroll
  for (int i = 0; i < 8; ++i) {
    const int e = i * 2048 + tid * 8;
    *reinterpret_cast<ushort8*>(&sW[e]) =
        *reinterpret_cast<const ushort8*>(&Wsrc[e]);
  }

  const int lane = tid & 63;
  const int wv = tid >> 6;
  const int lm = lane & 15;
  const int hi = lane >> 4;             // 0..3
  const int lk = hi * 8;
  const int row = chunk * 64 + wv * 16 + lm;

  // A-fragments: one 16-row tile per wave, coalesced bf16 loads.
  short8 Af[8];
  #pragma unroll
  for (int kk = 0; kk < 8; ++kk) {
    Af[kk] = *reinterpret_cast<const short8*>(
        &Xb[(size_t)row * 256 + kk * 32 + lk]);
  }

  const float* __restrict__ bias = (mat == 0) ? bq : (mat == 1) ? bk : bv;

  __syncthreads();

  #pragma unroll
  for (int nt = 0; nt < 4; ++nt) {
    short8 Bf[8];
    #pragma unroll
    for (int kk = 0; kk < 8; ++kk) {
      Bf[kk] = *reinterpret_cast<const short8*>(
          &sW[kk * 2048 + hi * 512 + (nt * 16 + lm) * 8]);
    }
    f32x4 acc = {0.f, 0.f, 0.f, 0.f};
    #pragma unroll
    for (int kk = 0; kk < 8; ++kk) {
      acc = __builtin_amdgcn_mfma_f32_16x16x32_bf16(Bf[kk], Af[kk], acc, 0, 0, 0);
    }
    const int col0 = c0 + nt * 16 + hi * 4;
    const float4 b4 = *reinterpret_cast<const float4*>(&bias[col0]);
    if (mat == 0) {
      float4 o;
      o.x = acc[0] + b4.x; o.y = acc[1] + b4.y;
      o.z = acc[2] + b4.z; o.w = acc[3] + b4.w;
      *reinterpret_cast<float4*>(&Qs[(size_t)row * 256 + col0]) = o;
    } else {
      u16x4 o;
      o[0] = f2bf(acc[0] + b4.x); o[1] = f2bf(acc[1] + b4.y);
      o[2] = f2bf(acc[2] + b4.z); o[3] = f2bf(acc[3] + b4.w);
      unsigned short* __restrict__ dst = (mat == 1) ? Kb : Vb;
      *reinterpret_cast<u16x4*>(&dst[(size_t)row * 256 + col0]) = o;
    }
  }
}

// ---------------------------------------------------------------------------
// Attention with V-PREFETCH. One block per segment, 256 threads = 4 waves;
// wave wv owns heads {2wv, 2wv+1} in both phases -> s_w handoff wave-local
// (LDS fence only). Lane map: lane = j*4 + hh*2 + p.
// KEY CHANGE: the 16 V-gather loads (addresses depend only on edges) are
// issued at KERNEL ENTRY into registers, so their ~500cy latency overlaps
// the K-gather + softmax instead of serializing after the fence.
// Softmax without max-subtraction (validated R10+; inputs normalized).
// XCD swizzle kept (present in all measured attn configs).
// ---------------------------------------------------------------------------
__global__ __launch_bounds__(256) void attn_kernel(
    const float* __restrict__ Q, const unsigned short* __restrict__ K,
    const unsigned short* __restrict__ V, const int* __restrict__ edges,
    float* __restrict__ out) {
  __shared__ float s_w[DEG * NHEADS];   // [j][h], 512 B

  const int bx = blockIdx.x;
  const int xcd = bx & 7;
  const int g = (xcd >> 1) * NNODES + (((bx >> 3) << 1) | (xcd & 1));
  const int e0 = g * DEG;
  const int tid = threadIdx.x;

  const int b = edges[e0];                            // block-uniform
  const int bN = b * NNODES;
  const int qrow = bN + edges[NEDGES + e0];           // block-uniform

  // ---- V-prefetch: issue all 16 gathers NOW (tid = channel) ----
  unsigned short vraw[DEG];
  #pragma unroll
  for (int jj = 0; jj < DEG; ++jj) {
    const int n = bN + edges[2 * NEDGES + e0 + jj];   // uniform scalar loads
    vraw[jj] = V[(size_t)n * HID + tid];              // coalesced 128B/wave-row
  }

  // ---- Phase 1 + in-wave softmax ----
  const int lane = tid & 63;
  const int wv = tid >> 6;
  const int j = lane >> 2;
  const int hh = (lane >> 1) & 1;
  const int p = lane & 1;
  const int h = wv * 2 + hh;
  const int ch0 = h * 32 + p * 16;

  const int nsrc = bN + edges[2 * NEDGES + e0 + j];   // 16 distinct, coalesced

  const float* __restrict__ qp = &Q[(size_t)qrow * HID + ch0];
  const float4 q0 = *reinterpret_cast<const float4*>(qp);
  const float4 q1 = *reinterpret_cast<const float4*>(qp + 4);
  const float4 q2 = *reinterpret_cast<const float4*>(qp + 8);
  const float4 q3 = *reinterpret_cast<const float4*>(qp + 12);
  const unsigned short* __restrict__ kp = &K[(size_t)nsrc * HID + ch0];
  const ushort8 k0 = *reinterpret_cast<const ushort8*>(kp);
  const ushort8 k1 = *reinterpret_cast<const ushort8*>(kp + 8);

  float partial;
  partial  = q0.x * bf2f(k0[0]); partial = fmaf(q0.y, bf2f(k0[1]), partial);
  partial = fmaf(q0.z, bf2f(k0[2]), partial); partial = fmaf(q0.w, bf2f(k0[3]), partial);
  partial = fmaf(q1.x, bf2f(k0[4]), partial); partial = fmaf(q1.y, bf2f(k0[5]), partial);
  partial = fmaf(q1.z, bf2f(k0[6]), partial); partial = fmaf(q1.w, bf2f(k0[7]), partial);
  partial = fmaf(q2.x, bf2f(k1[0]), partial); partial = fmaf(q2.y, bf2f(k1[1]), partial);
  partial = fmaf(q2.z, bf2f(k1[2]), partial); partial = fmaf(q2.w, bf2f(k1[3]), partial);
  partial = fmaf(q3.x, bf2f(k1[4]), partial); partial = fmaf(q3.y, bf2f(k1[5]), partial);
  partial = fmaf(q3.z, bf2f(k1[6]), partial); partial = fmaf(q3.w, bf2f(k1[7]), partial);

  partial += __shfl_xor(partial, 1);                 // combine p-halves
  const float sc = partial * 0.17677669529663687f;   // 1/sqrt(DH)

  const float e = __expf(sc);                        // no max shift (safe: |sc| small)
  float sum = e;
  sum += __shfl_xor(sum, 4);
  sum += __shfl_xor(sum, 8);
  sum += __shfl_xor(sum, 16);
  sum += __shfl_xor(sum, 32);

  if (p == 0) s_w[j * NHEADS + h] = e / sum;
  // Wave-local handoff: fence LDS, no all-wave barrier needed.
  asm volatile("s_waitcnt lgkmcnt(0)" ::: "memory");

  // ---- Phase 3: weighted sum of prefetched V (tid = channel) ----
  const int h3 = tid >> 5;
  float acc = 0.0f;
  #pragma unroll
  for (int jj = 0; jj < DEG; ++jj) {
    acc = fmaf(s_w[jj * NHEADS + h3], bf2f(vraw[jj]), acc);
  }
  out[(size_t)qrow * HID + tid] = acc;
}

// ---------------------------------------------------------------------------
extern "C" void kernel_launch(void* const* d_in, const int* in_sizes, int n_in,
                              void* d_out, int out_size, void* d_ws, size_t ws_size,
                              hipStream_t stream) {
  const float* X     = (const float*)d_in[0];
  const int*   edges = (const int*)d_in[1];
  const float* Wq    = (const float*)d_in[2];
  const float* bq    = (const float*)d_in[3];
  const float* Wk    = (const float*)d_in[4];
  const float* bk    = (const float*)d_in[5];
  const float* Wv    = (const float*)d_in[6];
  const float* bv    = (const float*)d_in[7];
  float* out = (float*)d_out;

  // Workspace: Qs fp32 16MiB | Kb bf16 8MiB | Vb bf16 8MiB | Xb bf16 8MiB |
  //            Wt bf16 384KiB  (~40.4 MiB total)
  char* w = (char*)d_ws;
  float*          Qs = (float*)w;                 w += (size_t)NROWS * HID * 4;
  unsigned short* Kb = (unsigned short*)w;        w += (size_t)NROWS * HID * 2;
  unsigned short* Vb = (unsigned short*)w;        w += (size_t)NROWS * HID * 2;
  unsigned short* Xb = (unsigned short*)w;        w += (size_t)NROWS * HID * 2;
  unsigned short* Wt = (unsigned short*)w;

  prep_kernel<<<XBLOCKS + WBLOCKS, 256, 0, stream>>>(X, Wq, Wk, Wv, Xb, Wt);
  qkv_mfma_kernel<<<3072, 256, 0, stream>>>(Xb, Wt, bq, bk, bv, Qs, Kb, Vb);
  attn_kernel<<<NROWS, 256, 0, stream>>>(Qs, Kb, Vb, edges, out);
}

// Round 13
// 61.154 us; speedup vs baseline: 1.1635x; 1.0200x over previous
//
#include <hip/hip_runtime.h>
#include <hip/hip_bf16.h>

// Problem constants (fixed by setup_inputs)
#define BATCH 4
#define NNODES 4096
#define HID 256
#define NHEADS 8
#define DH 32
#define DEG 16
#define NEDGES (BATCH * NNODES * DEG)   // 262144
#define NROWS (BATCH * NNODES)          // 16384 node-rows

typedef __attribute__((ext_vector_type(8))) short short8;
typedef __attribute__((ext_vector_type(8))) unsigned short ushort8;
typedef __attribute__((ext_vector_type(4))) unsigned short u16x4;  // 'ushort4' collides with HIP types
typedef __attribute__((ext_vector_type(4))) float f32x4;

static __device__ __forceinline__ unsigned short f2bf(float f) {
  __hip_bfloat16 h = __float2bfloat16(f);  // RNE
  return *reinterpret_cast<unsigned short*>(&h);
}
static __device__ __forceinline__ float bf2f(unsigned short u) {
  unsigned int v = ((unsigned int)u) << 16;
  return *reinterpret_cast<float*>(&v);
}

// ---------------------------------------------------------------------------
// Prep (unchanged): X -> bf16 row-major Xb (blocks [0,2048)); Wt
// fragment-ordered bf16 (96 blocks):
//   Wt[(mat*4+strip)*16384 + kk*2048 + hi*512 + col*8 + j]
//     = bf16( W_mat[kk*32 + hi*8 + j][strip*64 + col] )
// ---------------------------------------------------------------------------
#define XBLOCKS 2048
#define WBLOCKS 96
__global__ __launch_bounds__(256) void prep_kernel(
    const float* __restrict__ X,
    const float* __restrict__ Wq, const float* __restrict__ Wk,
    const float* __restrict__ Wv,
    unsigned short* __restrict__ Xb, unsigned short* __restrict__ Wt) {
  const int tid = threadIdx.x;
  if (blockIdx.x < XBLOCKS) {
    const size_t base = (size_t)blockIdx.x * 2048 + (size_t)tid * 8;
    const float4 a = *reinterpret_cast<const float4*>(&X[base]);
    const float4 b = *reinterpret_cast<const float4*>(&X[base + 4]);
    ushort8 o;
    o[0] = f2bf(a.x); o[1] = f2bf(a.y); o[2] = f2bf(a.z); o[3] = f2bf(a.w);
    o[4] = f2bf(b.x); o[5] = f2bf(b.y); o[6] = f2bf(b.z); o[7] = f2bf(b.w);
    *reinterpret_cast<ushort8*>(&Xb[base]) = o;
  } else {
    const int o = (blockIdx.x - XBLOCKS) * 2048 + tid * 8;  // [0, 196608)
    const int mat   = o >> 16;
    const int w     = o & 65535;
    const int strip = w >> 14;
    const int r     = w & 16383;
    const int kk    = r >> 11;
    const int hi    = (r >> 9) & 3;
    const int col   = (r >> 3) & 63;
    const int k0    = kk * 32 + hi * 8;
    const int c     = strip * 64 + col;
    const float* __restrict__ W = (mat == 0) ? Wq : (mat == 1) ? Wk : Wv;
    ushort8 ovec;
    #pragma unroll
    for (int j = 0; j < 8; ++j) {
      ovec[j] = f2bf(W[(size_t)(k0 + j) * HID + c]);
    }
    *reinterpret_cast<ushort8*>(&Wt[o]) = ovec;
  }
}

// ---------------------------------------------------------------------------
// QKV projection (unchanged R5 structure — best measured, ~26 us).
// Grid 3072, STRIP-MAJOR: s = bx>>8 (mat = s>>2, cols [(s&3)*64,+64)),
// chunk = bx&255 (64 rows). LDS-W linear conflict-free stage; A-frags per
// wave; 4 nt-tiles x 8 MFMA (swapped operands); vector stores.
// ---------------------------------------------------------------------------
__global__ __launch_bounds__(256, 4) void qkv_mfma_kernel(
    const unsigned short* __restrict__ Xb, const unsigned short* __restrict__ Wt,
    const float* __restrict__ bq, const float* __restrict__ bk,
    const float* __restrict__ bv,
    float* __restrict__ Qs, unsigned short* __restrict__ Kb,
    unsigned short* __restrict__ Vb) {
  __shared__ unsigned short sW[16384];  // 32 KB

  const int tid = threadIdx.x;
  const int s = blockIdx.x >> 8;        // 0..11  (strip-major)
  const int chunk = blockIdx.x & 255;   // 0..255
  const int mat = s >> 2;               // 0=Q 1=K 2=V
  const int c0 = (s & 3) * 64;

  const unsigned short* __restrict__ Wsrc = Wt + (size_t)(mat * 4 + (s & 3)) * 16384;
  #pragma unroll
  for (int i = 0; i < 8; ++i) {
    const int e = i * 2048 + tid * 8;
    *reinterpret_cast<ushort8*>(&sW[e]) =
        *reinterpret_cast<const ushort8*>(&Wsrc[e]);
  }

  const int lane = tid & 63;
  const int wv = tid >> 6;
  const int lm = lane & 15;
  const int hi = lane >> 4;             // 0..3
  const int lk = hi * 8;
  const int row = chunk * 64 + wv * 16 + lm;

  short8 Af[8];
  #pragma unroll
  for (int kk = 0; kk < 8; ++kk) {
    Af[kk] = *reinterpret_cast<const short8*>(
        &Xb[(size_t)row * 256 + kk * 32 + lk]);
  }

  const float* __restrict__ bias = (mat == 0) ? bq : (mat == 1) ? bk : bv;

  __syncthreads();

  #pragma unroll
  for (int nt = 0; nt < 4; ++nt) {
    short8 Bf[8];
    #pragma unroll
    for (int kk = 0; kk < 8; ++kk) {
      Bf[kk] = *reinterpret_cast<const short8*>(
          &sW[kk * 2048 + hi * 512 + (nt * 16 + lm) * 8]);
    }
    f32x4 acc = {0.f, 0.f, 0.f, 0.f};
    #pragma unroll
    for (int kk = 0; kk < 8; ++kk) {
      acc = __builtin_amdgcn_mfma_f32_16x16x32_bf16(Bf[kk], Af[kk], acc, 0, 0, 0);
    }
    const int col0 = c0 + nt * 16 + hi * 4;
    const float4 b4 = *reinterpret_cast<const float4*>(&bias[col0]);
    if (mat == 0) {
      float4 o;
      o.x = acc[0] + b4.x; o.y = acc[1] + b4.y;
      o.z = acc[2] + b4.z; o.w = acc[3] + b4.w;
      *reinterpret_cast<float4*>(&Qs[(size_t)row * 256 + col0]) = o;
    } else {
      u16x4 o;
      o[0] = f2bf(acc[0] + b4.x); o[1] = f2bf(acc[1] + b4.y);
      o[2] = f2bf(acc[2] + b4.z); o[3] = f2bf(acc[3] + b4.w);
      unsigned short* __restrict__ dst = (mat == 1) ? Kb : Vb;
      *reinterpret_cast<u16x4*>(&dst[(size_t)row * 256 + col0]) = o;
    }
  }
}

// ---------------------------------------------------------------------------
// Attention, V-prefetch with CORRECT ISSUE ORDER. One block per segment,
// 256 threads = 4 waves; wave wv owns heads {2wv,2wv+1} in both phases ->
// s_w handoff wave-local (LDS fence only). Lane map: lane = j*4 + hh*2 + p.
//
// vmcnt is a FIFO over issue order (cdna4_isa §8): waiting for a LATER load
// drains all EARLIER ones. R12 issued the 16 slow V-gathers first, so the
// K-wait in phase 1 drained every V load -> V latency sat IN FRONT of the
// critical path. Fix: issue K, then Q, THEN the V-prefetch. Phase 1's K/Q
// wait leaves the 16 V loads outstanding; their latency hides under the
// dot-product + softmax; phase 3 drains the remainder.
// Softmax without max-subtraction (validated; inputs normalized).
// ---------------------------------------------------------------------------
__global__ __launch_bounds__(256) void attn_kernel(
    const float* __restrict__ Q, const unsigned short* __restrict__ K,
    const unsigned short* __restrict__ V, const int* __restrict__ edges,
    float* __restrict__ out) {
  __shared__ float s_w[DEG * NHEADS];   // [j][h], 512 B

  const int bx = blockIdx.x;
  const int xcd = bx & 7;
  const int g = (xcd >> 1) * NNODES + (((bx >> 3) << 1) | (xcd & 1));
  const int e0 = g * DEG;
  const int tid = threadIdx.x;

  const int b = edges[e0];                            // block-uniform
  const int bN = b * NNODES;
  const int qrow = bN + edges[NEDGES + e0];           // block-uniform

  const int lane = tid & 63;
  const int wv = tid >> 6;
  const int j = lane >> 2;
  const int hh = (lane >> 1) & 1;
  const int p = lane & 1;
  const int h = wv * 2 + hh;
  const int ch0 = h * 32 + p * 16;

  // ---- Issue K FIRST (needed first) ----
  const int nsrc = bN + edges[2 * NEDGES + e0 + j];   // 16 distinct, coalesced
  const unsigned short* __restrict__ kp = &K[(size_t)nsrc * HID + ch0];
  const ushort8 k0 = *reinterpret_cast<const ushort8*>(kp);
  const ushort8 k1 = *reinterpret_cast<const ushort8*>(kp + 8);

  // ---- Then Q ----
  const float* __restrict__ qp = &Q[(size_t)qrow * HID + ch0];
  const float4 q0 = *reinterpret_cast<const float4*>(qp);
  const float4 q1 = *reinterpret_cast<const float4*>(qp + 4);
  const float4 q2 = *reinterpret_cast<const float4*>(qp + 8);
  const float4 q3 = *reinterpret_cast<const float4*>(qp + 12);

  // ---- Then V-prefetch (stays outstanding across phase 1 + softmax) ----
  unsigned short vraw[DEG];
  #pragma unroll
  for (int jj = 0; jj < DEG; ++jj) {
    const int n = bN + edges[2 * NEDGES + e0 + jj];   // uniform scalar loads
    vraw[jj] = V[(size_t)n * HID + tid];              // coalesced 128B/wave
  }

  // ---- Phase 1: dot + in-wave softmax (waits only on K/Q) ----
  float partial;
  partial  = q0.x * bf2f(k0[0]); partial = fmaf(q0.y, bf2f(k0[1]), partial);
  partial = fmaf(q0.z, bf2f(k0[2]), partial); partial = fmaf(q0.w, bf2f(k0[3]), partial);
  partial = fmaf(q1.x, bf2f(k0[4]), partial); partial = fmaf(q1.y, bf2f(k0[5]), partial);
  partial = fmaf(q1.z, bf2f(k0[6]), partial); partial = fmaf(q1.w, bf2f(k0[7]), partial);
  partial = fmaf(q2.x, bf2f(k1[0]), partial); partial = fmaf(q2.y, bf2f(k1[1]), partial);
  partial = fmaf(q2.z, bf2f(k1[2]), partial); partial = fmaf(q2.w, bf2f(k1[3]), partial);
  partial = fmaf(q3.x, bf2f(k1[4]), partial); partial = fmaf(q3.y, bf2f(k1[5]), partial);
  partial = fmaf(q3.z, bf2f(k1[6]), partial); partial = fmaf(q3.w, bf2f(k1[7]), partial);

  partial += __shfl_xor(partial, 1);                 // combine p-halves
  const float sc = partial * 0.17677669529663687f;   // 1/sqrt(DH)

  const float e = __expf(sc);                        // no max shift (safe: |sc| small)
  float sum = e;
  sum += __shfl_xor(sum, 4);
  sum += __shfl_xor(sum, 8);
  sum += __shfl_xor(sum, 16);
  sum += __shfl_xor(sum, 32);

  if (p == 0) s_w[j * NHEADS + h] = e / sum;
  // Wave-local handoff: fence LDS, no all-wave barrier needed.
  asm volatile("s_waitcnt lgkmcnt(0)" ::: "memory");

  // ---- Phase 3: weighted sum of prefetched V (tid = channel) ----
  const int h3 = tid >> 5;
  float acc = 0.0f;
  #pragma unroll
  for (int jj = 0; jj < DEG; ++jj) {
    acc = fmaf(s_w[jj * NHEADS + h3], bf2f(vraw[jj]), acc);
  }
  out[(size_t)qrow * HID + tid] = acc;
}

// ---------------------------------------------------------------------------
extern "C" void kernel_launch(void* const* d_in, const int* in_sizes, int n_in,
                              void* d_out, int out_size, void* d_ws, size_t ws_size,
                              hipStream_t stream) {
  const float* X     = (const float*)d_in[0];
  const int*   edges = (const int*)d_in[1];
  const float* Wq    = (const float*)d_in[2];
  const float* bq    = (const float*)d_in[3];
  const float* Wk    = (const float*)d_in[4];
  const float* bk    = (const float*)d_in[5];
  const float* Wv    = (const float*)d_in[6];
  const float* bv    = (const float*)d_in[7];
  float* out = (float*)d_out;

  // Workspace: Qs fp32 16MiB | Kb bf16 8MiB | Vb bf16 8MiB | Xb bf16 8MiB |
  //            Wt bf16 384KiB  (~40.4 MiB total)
  char* w = (char*)d_ws;
  float*          Qs = (float*)w;                 w += (size_t)NROWS * HID * 4;
  unsigned short* Kb = (unsigned short*)w;        w += (size_t)NROWS * HID * 2;
  unsigned short* Vb = (unsigned short*)w;        w += (size_t)NROWS * HID * 2;
  unsigned short* Xb = (unsigned short*)w;        w += (size_t)NROWS * HID * 2;
  unsigned short* Wt = (unsigned short*)w;

  prep_kernel<<<XBLOCKS + WBLOCKS, 256, 0, stream>>>(X, Wq, Wk, Wv, Xb, Wt);
  qkv_mfma_kernel<<<3072, 256, 0, stream>>>(Xb, Wt, bq, bk, bv, Qs, Kb, Vb);
  attn_kernel<<<NROWS, 256, 0, stream>>>(Qs, Kb, Vb, edges, out);
}